// Round 4
// 202.324 us; speedup vs baseline: 1.0021x; 1.0021x over previous
//
#include <hip/hip_runtime.h>
#include <stdint.h>
#include <math.h>

static constexpr int TOPK  = 8;
static constexpr int TOPKG = 4;
static constexpr int NEXP  = 256;
static constexpr float RSF = 2.5f;

// DPP control codes
static constexpr int DPP_QX1 = 0xB1;  // quad_perm [1,0,3,2]  == xor1
static constexpr int DPP_QX2 = 0x4E;  // quad_perm [2,3,0,1]  == xor2
static constexpr int DPP_HM  = 0x141; // row_half_mirror      == xor4 once quads uniform
static constexpr int DPP_MIR = 0x140; // row_mirror           == xor8 once 8-blocks uniform

template <int CTRL>
__device__ __forceinline__ float dppmov_f(float x) {
    int xi = __float_as_int(x);
    return __int_as_float(__builtin_amdgcn_update_dpp(xi, xi, CTRL, 0xF, 0xF, false));
}
template <int CTRL>
__device__ __forceinline__ uint32_t dppmov_u(uint32_t x) {
    return (uint32_t)__builtin_amdgcn_update_dpp((int)x, (int)x, CTRL, 0xF, 0xF, false);
}

// monotonic f32 -> u32 (order-preserving, bijective)
__device__ __forceinline__ uint32_t f2sort(float f) {
    uint32_t u = __float_as_uint(f);
    return u ^ ((uint32_t)((int32_t)u >> 31) | 0x80000000u);
}

// descending compare-exchange (u32 keys) with index payload; stable on ties
__device__ __forceinline__ void cas(uint32_t& ax, uint32_t& ay, int& ix, int& iy) {
    bool p      = ax < ay;
    uint32_t hi = p ? ay : ax, lo = p ? ax : ay;
    int nx      = p ? iy : ix,  ny = p ? ix : iy;
    ax = hi; ay = lo; ix = nx; iy = ny;
}

__global__ __launch_bounds__(256) void router_kernel(
    const float* __restrict__ logits,   // [T, 256]
    const float* __restrict__ bias,     // [256]
    float* __restrict__ out_w,          // [T, 8]
    float* __restrict__ out_id,         // [T, 8] (ids as float)
    int T)
{
    const int lane  = threadIdx.x & 63;
    const int token = blockIdx.x * (blockDim.x >> 6) + (threadIdx.x >> 6);
    if (token >= T) return;

    const float* row = logits + (size_t)token * NEXP;
    float4 v = ((const float4*)row)[lane];
    float4 b = ((const float4*)bias)[lane];

    float s0 = v.x + b.x;
    float s1 = v.y + b.y;
    float s2 = v.z + b.z;
    float s3 = v.w + b.w;

    // ---- group score: sum of top-2 biased scores per 8-lane (32-expert) group ----
    float hi01 = fmaxf(s0, s1), lo01 = fminf(s0, s1);
    float hi23 = fmaxf(s2, s3), lo23 = fminf(s2, s3);
    float m1 = fmaxf(hi01, hi23);
    float m2 = fmaxf(fminf(hi01, hi23), fmaxf(lo01, lo23));
    {
        float o1 = dppmov_f<DPP_QX1>(m1), o2 = dppmov_f<DPP_QX1>(m2);
        float n1 = fmaxf(m1, o1);
        float n2 = fmaxf(fminf(m1, o1), fmaxf(m2, o2));
        m1 = n1; m2 = n2;
    }
    {
        float o1 = dppmov_f<DPP_QX2>(m1), o2 = dppmov_f<DPP_QX2>(m2);
        float n1 = fmaxf(m1, o1);
        float n2 = fmaxf(fminf(m1, o1), fmaxf(m2, o2));
        m1 = n1; m2 = n2;
    }
    {
        float o1 = dppmov_f<DPP_HM>(m1), o2 = dppmov_f<DPP_HM>(m2);
        float n1 = fmaxf(m1, o1);
        float n2 = fmaxf(fminf(m1, o1), fmaxf(m2, o2));
        m1 = n1; m2 = n2;
    }
    const float gscore = m1 + m2;   // uniform within each 8-lane group

    // ---- group rank: shuffle-transpose + ballot + windowed popcount ----
    const int g = lane >> 3;
    const int j = lane & 7;
    float gj = __shfl(gscore, j << 3, 64);
    bool beats = (gj > gscore) || (gj == gscore && j < g);
    uint64_t balg = __ballot(beats);
    int rank = __popcll(balg & (0xFFull << (g << 3)));
    const bool sel = (rank < TOPKG);

    // ---- sortable keys (masked -> 0), per-lane descending sort of 4 ----
    uint32_t a0 = sel ? f2sort(s0) : 0u;
    uint32_t a1 = sel ? f2sort(s1) : 0u;
    uint32_t a2 = sel ? f2sort(s2) : 0u;
    uint32_t a3 = sel ? f2sort(s3) : 0u;
    const int ebase = lane << 2;
    int i0 = ebase, i1 = ebase + 1, i2 = ebase + 2, i3 = ebase + 3;
    cas(a0, a1, i0, i1);
    cas(a2, a3, i2, i3);
    cas(a0, a2, i0, i2);
    cas(a1, a3, i1, i3);
    cas(a1, a2, i1, i2);
    uint32_t ipack = (uint32_t)i0 | ((uint32_t)i1 << 8) |
                     ((uint32_t)i2 << 16) | ((uint32_t)i3 << 24);

    // ---- init per-16-block head maxima (SGPR-cached) ----
    uint32_t bm = a0;
    bm = max(bm, dppmov_u<DPP_QX1>(bm));
    bm = max(bm, dppmov_u<DPP_QX2>(bm));
    bm = max(bm, dppmov_u<DPP_HM >(bm));
    bm = max(bm, dppmov_u<DPP_MIR>(bm));          // block-of-16 max in all its lanes
    uint32_t rm0 = (uint32_t)__builtin_amdgcn_readlane((int)bm,  0);
    uint32_t rm1 = (uint32_t)__builtin_amdgcn_readlane((int)bm, 16);
    uint32_t rm2 = (uint32_t)__builtin_amdgcn_readlane((int)bm, 32);
    uint32_t rm3 = (uint32_t)__builtin_amdgcn_readlane((int)bm, 48);

    int myid = 0;

    // One selection round. R must be a numeric literal: the writelane lane
    // select is baked into the asm string (#R) so the instruction reads only
    // ONE SGPR (idx) — the two-SGPR form violates the constant-bus limit
    // (round-3 compile failure). writelane ignores exec; all 64 lanes live.
    // Round 7 keeps only the id extraction; deeper shift levels are trimmed
    // in late rounds (a value at depth d needs d more wins to surface).
#define ROUND(R)                                                              \
    {                                                                         \
        const uint32_t smax = max(max(rm0, rm1), max(rm2, rm3));              \
        const uint64_t bal = __ballot(a0 == smax);                            \
        const int wl  = __ffsll((unsigned long long)bal) - 1;                 \
        const int idx = __builtin_amdgcn_readlane((int)ipack, wl) & 255;      \
        asm("v_writelane_b32 %0, %1, " #R : "+v"(myid) : "s"(idx));           \
        if (R < 7) {                                                          \
            const bool win = (lane == wl);                                    \
            a0 = win ? a1 : a0;                                               \
            if (R < 6) a1 = win ? a2 : a1;                                    \
            if (R < 5) a2 = win ? a3 : a2;                                    \
            if (R < 4) a3 = win ? 0u : a3;                                    \
            ipack = win ? (ipack >> 8) : ipack;                               \
            uint32_t nb = a0;                                                 \
            nb = max(nb, dppmov_u<DPP_QX1>(nb));                              \
            nb = max(nb, dppmov_u<DPP_QX2>(nb));                              \
            nb = max(nb, dppmov_u<DPP_HM >(nb));                              \
            nb = max(nb, dppmov_u<DPP_MIR>(nb));                              \
            const uint32_t nbm =                                              \
                (uint32_t)__builtin_amdgcn_readlane((int)nb, wl);             \
            const int blk = wl >> 4;                                          \
            rm0 = (blk == 0) ? nbm : rm0;                                     \
            rm1 = (blk == 1) ? nbm : rm1;                                     \
            rm2 = (blk == 2) ? nbm : rm2;                                     \
            rm3 = (blk == 3) ? nbm : rm3;                                     \
        }                                                                     \
    }

    ROUND(0) ROUND(1) ROUND(2) ROUND(3)
    ROUND(4) ROUND(5) ROUND(6) ROUND(7)
#undef ROUND

    // ---- epilogue: exact unbiased gather (L1-hot), 8-lane sum, store ----
    float w = 0.f;
    if (lane < TOPK) w = row[myid];
    float t = w;
    t += dppmov_f<DPP_QX1>(t);
    t += dppmov_f<DPP_QX2>(t);
    t += dppmov_f<DPP_HM >(t);                    // lanes 0..7 hold the 8-sum

    if (lane < TOPK) {
        // keep exact IEEE division: absmax is already at 2^-9 (ill-conditioned
        // renorm denominators) — rcp-based division risks crossing tolerance.
        out_w [(size_t)token * TOPK + lane] = w / t * RSF;
        out_id[(size_t)token * TOPK + lane] = (float)myid;
    }
}

extern "C" void kernel_launch(void* const* d_in, const int* in_sizes, int n_in,
                              void* d_out, int out_size, void* d_ws, size_t ws_size,
                              hipStream_t stream) {
    const float* logits = (const float*)d_in[0];
    const float* bias   = (const float*)d_in[1];
    const int T = in_sizes[0] / NEXP;   // 131072
    float* out = (float*)d_out;
    float* out_w  = out;
    float* out_id = out + (size_t)T * TOPK;

    const int waves_per_block = 256 / 64;
    const int blocks = (T + waves_per_block - 1) / waves_per_block;
    router_kernel<<<blocks, 256, 0, stream>>>(logits, bias, out_w, out_id, T);
}